// Round 9
// baseline (135.335 us; speedup 1.0000x reference)
//
#include <hip/hip_runtime.h>

#define TT 2048
#define DD 384

typedef float f32x4 __attribute__((ext_vector_type(4)));
typedef float f32x16 __attribute__((ext_vector_type(16)));
typedef short s16x8 __attribute__((ext_vector_type(8)));
typedef short s16x2 __attribute__((ext_vector_type(2)));
typedef unsigned int u32x4 __attribute__((ext_vector_type(4)));
typedef unsigned int u32x2 __attribute__((ext_vector_type(2)));

typedef __attribute__((address_space(3))) unsigned char* as3p;
typedef const __attribute__((address_space(1))) unsigned char* as1p;
// HW direct global->LDS copy: 16B/lane x 64 lanes = 1KB per call; LDS dest = uniform base + lane*16.
#define GLLDS(gsrc, ldst) __builtin_amdgcn_global_load_lds((as1p)(gsrc), (as3p)(ldst), 16, 0, 0)

static __device__ __forceinline__ unsigned short f2bf(float f) {
    unsigned int u = __builtin_bit_cast(unsigned int, f);
    u = (u + 0x7fffu + ((u >> 16) & 1u)) >> 16;
    return (unsigned short)u;
}
static __device__ __forceinline__ unsigned int pk2(float a, float b) {
#if __has_builtin(__builtin_amdgcn_cvt_pk_bf16_f32)
    s16x2 t = __builtin_amdgcn_cvt_pk_bf16_f32(a, b);
    return __builtin_bit_cast(unsigned int, t);
#else
    unsigned int ua = __builtin_bit_cast(unsigned int, a);
    unsigned int ub = __builtin_bit_cast(unsigned int, b);
    ua = (ua + 0x7fffu + ((ua >> 16) & 1u)) >> 16;
    ub = (ub + 0x7fffu + ((ub >> 16) & 1u)) & 0xffff0000u;
    return ua | ub;
#endif
}

// ---------------- x pre-conversion: xbf[m][k] bf16, A-tile LDS-image swizzle ----------------
// Within each (row m, 32-k group): 8-elt chunk c stored at c^(m&3) — the exact image qkv_gemm's
// A-frag reads expect, so A staging becomes pure global_load_lds (verified layout, R4 xwprep).
__global__ __launch_bounds__(256, 8) void xprep(
    const float* __restrict__ x, unsigned short* __restrict__ xbf)
{
    const int gid = blockIdx.x * 256 + threadIdx.x;   // 786432 = 16384 rows x 48 chunks
    const int m  = gid / 48;
    const int cc = gid % 48;
    const int kt = cc >> 2, c = cc & 3;
    const float* xp = x + (size_t)m * 384 + kt * 32 + c * 8;
    f32x4 a = *(const f32x4*)xp;
    f32x4 b = *(const f32x4*)(xp + 4);
    u32x4 v = (u32x4){pk2(a[0], a[1]), pk2(a[2], a[3]), pk2(b[0], b[1]), pk2(b[2], b[3])};
    *(s16x8*)(xbf + (size_t)m * 384 + kt * 32 + ((c ^ (m & 3)) * 8)) = __builtin_bit_cast(s16x8, v);
}

// ---------------- W pre-conversion: wall[512 col][384 k] bf16, B-tile LDS-image swizzle ----------
// col 0..63 = Wq, 64..127 = Wk, 128..511 = Wv; chunk c stored at c ^ (col&3).
__global__ __launch_bounds__(256, 8) void wprep(
    const float* __restrict__ Wq, const float* __restrict__ Wk, const float* __restrict__ Wv,
    unsigned short* __restrict__ wall)
{
    const int gid = blockIdx.x * 256 + threadIdx.x;   // 6144 = 512 cols x 12 k-groups
    const int col = gid & 511;
    const int kt  = gid >> 9;
    unsigned short* op = wall + (size_t)col * 384 + kt * 32;
    #pragma unroll
    for (int c = 0; c < 4; ++c) {
        u32x4 v;
        #pragma unroll
        for (int j2 = 0; j2 < 4; ++j2) {
            const int k = kt * 32 + c * 8 + j2 * 2;
            float f0 = (col < 64)  ? Wq[(size_t)k * 64 + col]
                     : (col < 128) ? Wk[(size_t)k * 64 + (col - 64)]
                                   : Wv[(size_t)k * 384 + (col - 128)];
            float f1 = (col < 64)  ? Wq[(size_t)(k + 1) * 64 + col]
                     : (col < 128) ? Wk[(size_t)(k + 1) * 64 + (col - 64)]
                                   : Wv[(size_t)(k + 1) * 384 + (col - 128)];
            v[j2] = pk2(f0, f1);
        }
        *(s16x8*)(op + ((c ^ (col & 3)) * 8)) = __builtin_bit_cast(s16x8, v);
    }
}

// ---------------- fused QKV projection GEMM R9: 64x128 tiles, all-GLLDS staging, 4 blocks/CU ------
// A (xbf) and B (wall) both pre-swizzled bf16 -> staging is 3 global_load_lds per wave per kt,
// ZERO conversion VALU in the loop. Grid (256,4) = 4 blocks/CU (R8's proven latency fix).
// Outputs byte-identical: q natural (1/8), k pre-swizzled, vT transposed pre-swizzled.
__global__ __launch_bounds__(256, 4) void qkv_gemm(
    const unsigned short* __restrict__ xbf, const unsigned short* __restrict__ wall,
    unsigned short* __restrict__ qo, unsigned short* __restrict__ ko,
    unsigned short* __restrict__ vto)
{
    __shared__ __align__(16) unsigned short lds[12288];   // 2 bufs x (A 2048 | B 4096) ush
    const int tid = threadIdx.x;
    const int l   = tid & 63;
    const int w   = tid >> 6;
    const int si  = l & 15;
    const int qq  = l >> 4;
    const int m0  = blockIdx.x * 64;
    const int nb  = blockIdx.y;
    const int wr  = w >> 1, wc = w & 1;

    const unsigned short* as = xbf + (size_t)m0 * 384;
    const unsigned short* ws = wall + (size_t)nb * 128 * 384;   // this nb's 128-col panel

#define QSTAGE(KT, B)                                                                      \
    {                                                                                      \
        GLLDS(as + (size_t)(w * 16 + (l >> 2)) * 384 + (KT) * 32 + (l & 3) * 8,            \
              &lds[(B) * 6144 + w * 512]);                                                 \
        _Pragma("unroll")                                                                  \
        for (int c2 = 0; c2 < 2; ++c2) {                                                   \
            const int ch = w * 2 + c2;                                                     \
            GLLDS(ws + (size_t)(ch * 16 + (l >> 2)) * 384 + (KT) * 32 + (l & 3) * 8,       \
                  &lds[(B) * 6144 + 2048 + ch * 512]);                                     \
        }                                                                                  \
    }

    f32x4 acc[2][4];
    #pragma unroll
    for (int rt = 0; rt < 2; ++rt)
        #pragma unroll
        for (int ct = 0; ct < 4; ++ct) acc[rt][ct] = (f32x4){0.f, 0.f, 0.f, 0.f};

    QSTAGE(0, 0);
    for (int kt = 0; kt < 12; ++kt) {
        const int b = kt & 1;
        __syncthreads();                       // vmcnt(0)+barrier: buf b staged
        if (kt < 11) QSTAGE(kt + 1, 1 - b);

        s16x8 af[2], bf[4];
        #pragma unroll
        for (int rt = 0; rt < 2; ++rt) {
            const int row = wr * 32 + rt * 16 + si;
            af[rt] = *(const s16x8*)&lds[b * 6144 + row * 32 + ((qq ^ (row & 3)) * 8)];
        }
        #pragma unroll
        for (int ct = 0; ct < 4; ++ct) {
            const int col = wc * 64 + ct * 16 + si;
            bf[ct] = *(const s16x8*)&lds[b * 6144 + 2048 + col * 32 + ((qq ^ (col & 3)) * 8)];
        }
        #pragma unroll
        for (int rt = 0; rt < 2; ++rt)
            #pragma unroll
            for (int ct = 0; ct < 4; ++ct)
                acc[rt][ct] = __builtin_amdgcn_mfma_f32_16x16x32_bf16(af[rt], bf[ct], acc[rt][ct], 0, 0, 0);
    }
    __syncthreads();                           // all frag reads done before epilogue overlays LDS
#undef QSTAGE

    if (nb == 0) {
        if (wc == 0) {  // q: natural layout, fold 1/sqrt(K)
            #pragma unroll
            for (int rt = 0; rt < 2; ++rt)
                #pragma unroll
                for (int ct = 0; ct < 4; ++ct)
                    #pragma unroll
                    for (int r = 0; r < 4; ++r) {
                        const int m = m0 + wr * 32 + rt * 16 + qq * 4 + r;
                        qo[(size_t)m * 64 + ct * 16 + si] = f2bf(acc[rt][ct][r] * 0.125f);
                    }
        } else {        // k: pre-swizzled (chunk c -> c ^ (t&7))
            #pragma unroll
            for (int rt = 0; rt < 2; ++rt)
                #pragma unroll
                for (int ct = 0; ct < 4; ++ct)
                    #pragma unroll
                    for (int r = 0; r < 4; ++r) {
                        const int m = m0 + wr * 32 + rt * 16 + qq * 4 + r;
                        const int col = ct * 16 + si;
                        ko[(size_t)m * 64 + (((col >> 3) ^ (m & 7)) * 8) + (col & 7)] = f2bf(acc[rt][ct][r]);
                    }
        }
    } else {            // vT: transpose in LDS (pre-swizzled image), then linear 16B copy-out
        #pragma unroll
        for (int rt = 0; rt < 2; ++rt)
            #pragma unroll
            for (int ct = 0; ct < 4; ++ct)
                #pragma unroll
                for (int r = 0; r < 4; ++r) {
                    const int m = wr * 32 + rt * 16 + qq * 4 + r;   // local 0..63
                    const int n = wc * 64 + ct * 16 + si;           // 0..127
                    lds[n * 64 + (((m >> 3) ^ (n & 7)) * 8) + (m & 7)] = f2bf(acc[rt][ct][r]);
                }
        __syncthreads();
        const int bbat = m0 >> 11, t0 = m0 & 2047;
        #pragma unroll
        for (int i = 0; i < 4; ++i) {
            const int u = tid + 256 * i, n = u >> 3, p = u & 7;
            *(s16x8*)&vto[((size_t)bbat * DD + ((nb - 1) * 128 + n)) * TT + t0 + p * 8]
                = *(const s16x8*)&lds[n * 64 + p * 8];
        }
    }
}

// ---------------- fused causal attention R9: R6 base + split accumulator chains ----------------
// R6 structure (best measured): constant-work paired blocks, 256 blocks, 12 waves, lag-1 P
// pipeline, single barrier/iter. R9: PV accumulator split oa/ob by ss-parity (merged at epilogue)
// and QK chain split sa0/sa1 (merged before exp) — every dependent-MFMA chain halves (4->2),
// giving the 3 waves/SIMD enough independent MFMA work to hide matrix-pipe latency.
__global__ __launch_bounds__(768, 3) void attn(
    const unsigned short* __restrict__ qg, const unsigned short* __restrict__ kg,
    const unsigned short* __restrict__ vg, float* __restrict__ out)
{
    // ush map: kl [0,8192) = 2 x [64 t][64] | vl [8192,45056) = 3 x [192 e][64 t]
    //          pl [45056,53248) = 2 x [2 qh][2 ss][a0:512|a1:512] | stL overlays kl after loop
    __shared__ __align__(16) unsigned short lds[53248];

    const int tid = threadIdx.x;
    const int l   = tid & 63;
    const int w   = tid >> 6;     // 0..11
    const int qh  = w & 1;        // 32-row q half (within the 64-row tile)
    const int eu  = w >> 1;       // 0..5: 32-col e unit (consume role)
    const bool isprod = (w < 4);  // waves 0-3 produce subtile (qh, ss=eu)
    const int lo  = l & 31;
    const int hi  = l >> 5;

    const int g  = blockIdx.x;    // 0..255
    const int bb = g & 7;
    const int eh = (g >> 3) & 1;
    const int pr = g >> 4;        // 0..15 pair id
    const int e0 = eh * 192;

    const unsigned short* kbase = kg + (size_t)bb * TT * 64;
    const unsigned short* vbase = vg + ((size_t)bb * DD + e0) * TT;

    // staging: K 8 chunks by produce waves (2 each); V 24 chunks by waves 4..11 (3 each)
    #define STAGE(IT, KB, VB)                                                              \
    {                                                                                      \
        if (isprod) {                                                                      \
            GLLDS(kbase + (size_t)(IT) * 4096 + (2 * w) * 512 + l * 8,                     \
                  &lds[(KB) * 4096 + (2 * w) * 512]);                                      \
            GLLDS(kbase + (size_t)(IT) * 4096 + (2 * w + 1) * 512 + l * 8,                 \
                  &lds[(KB) * 4096 + (2 * w + 1) * 512]);                                  \
        } else {                                                                           \
            _Pragma("unroll")                                                              \
            for (int c3 = 0; c3 < 3; ++c3) {                                               \
                const int rg = 3 * (w - 4) + c3;                                           \
                GLLDS(vbase + (size_t)(rg * 8 + (l >> 3)) * TT + (IT) * 64 + (l & 7) * 8,  \
                      &lds[8192 + (VB) * 12288 + rg * 512]);                               \
            }                                                                              \
        }                                                                                  \
    }

    // PV consume: ss=0 -> oa, ss=1 -> ob (independent chains; merged at epilogue)
    #define PVSTEP(VB, PB)                                                                 \
    {                                                                                      \
        __builtin_amdgcn_s_setprio(1);                                                     \
        const int el = eu * 32 + lo;                                                       \
        const int vbse = 8192 + (VB) * 12288 + el * 64;                                    \
        {                                                                                  \
            const int pbse = 45056 + (PB) * 4096 + (qh * 2 + 0) * 1024;                    \
            s16x8 a0 = *(const s16x8*)&lds[pbse + l * 8];                                  \
            s16x8 a1 = *(const s16x8*)&lds[pbse + 512 + l * 8];                            \
            s16x8 v0 = *(const s16x8*)&lds[vbse + (((0 + hi) ^ (el & 7)) * 8)];            \
            oa = __builtin_amdgcn_mfma_f32_32x32x16_bf16(a0, v0, oa, 0, 0, 0);             \
            s16x8 v1 = *(const s16x8*)&lds[vbse + (((2 + hi) ^ (el & 7)) * 8)];            \
            oa = __builtin_amdgcn_mfma_f32_32x32x16_bf16(a1, v1, oa, 0, 0, 0);             \
        }                                                                                  \
        {                                                                                  \
            const int pbse = 45056 + (PB) * 4096 + (qh * 2 + 1) * 1024;                    \
            s16x8 a0 = *(const s16x8*)&lds[pbse + l * 8];                                  \
            s16x8 a1 = *(const s16x8*)&lds[pbse + 512 + l * 8];                            \
            s16x8 v0 = *(const s16x8*)&lds[vbse + (((4 + hi) ^ (el & 7)) * 8)];            \
            ob = __builtin_amdgcn_mfma_f32_32x32x16_bf16(a0, v0, ob, 0, 0, 0);             \
            s16x8 v1 = *(const s16x8*)&lds[vbse + (((6 + hi) ^ (el & 7)) * 8)];            \
            ob = __builtin_amdgcn_mfma_f32_32x32x16_bf16(a1, v1, ob, 0, 0, 0);             \
        }                                                                                  \
        __builtin_amdgcn_s_setprio(0);                                                     \
    }

    for (int hf = 0; hf < 2; ++hf) {
        const int q2 = hf ? pr : 31 - pr;      // heavy tile first, then its complement
        const int q0 = q2 * 64;
        const int qrow = q0 + qh * 32 + lo;

        // Q as B-operand frags (pre-scaled 1/8, natural layout) — produce waves only
        s16x8 qf[4];
        if (isprod) {
            const unsigned short* qp = qg + ((size_t)bb * TT + qrow) * 64;
            #pragma unroll
            for (int st = 0; st < 4; ++st) qf[st] = *(const s16x8*)(qp + st * 16 + hi * 8);
        }

        f32x16 oa, ob;
        #pragma unroll
        for (int r = 0; r < 16; ++r) { oa[r] = 0.f; ob[r] = 0.f; }
        float lp = 0.f;

        STAGE(0, 0, 0);   // prologue: tile 0 -> kl0 / vl0

        int vi = 0, vn = 1;   // vl slot of tile it, it+1 (mod 3); tile it-1 sits at the third slot
        for (int it = 0; it <= q2; ++it) {
            const int kb = it & 1;
            __syncthreads();   // vmcnt(0)+barrier: staging for tile it complete; pl[kb] free

            if (it < q2) STAGE(it + 1, 1 - kb, vn);   // in flight during compute

            if (isprod) {   // ---- produce P-subtile (qh, ss=eu) of tile it -> pl[kb] ----
                f32x16 sa0, sa1;
                #pragma unroll
                for (int r = 0; r < 16; ++r) { sa0[r] = 0.f; sa1[r] = 0.f; }
                __builtin_amdgcn_s_setprio(1);
                {
                    s16x8 kf0 = *(const s16x8*)&lds[kb * 4096 + (eu * 32 + lo) * 64 + (((0 + hi) ^ (lo & 7)) * 8)];
                    sa0 = __builtin_amdgcn_mfma_f32_32x32x16_bf16(kf0, qf[0], sa0, 0, 0, 0);
                    s16x8 kf1 = *(const s16x8*)&lds[kb * 4096 + (eu * 32 + lo) * 64 + (((2 + hi) ^ (lo & 7)) * 8)];
                    sa0 = __builtin_amdgcn_mfma_f32_32x32x16_bf16(kf1, qf[1], sa0, 0, 0, 0);
                    s16x8 kf2 = *(const s16x8*)&lds[kb * 4096 + (eu * 32 + lo) * 64 + (((4 + hi) ^ (lo & 7)) * 8)];
                    sa1 = __builtin_amdgcn_mfma_f32_32x32x16_bf16(kf2, qf[2], sa1, 0, 0, 0);
                    s16x8 kf3 = *(const s16x8*)&lds[kb * 4096 + (eu * 32 + lo) * 64 + (((6 + hi) ^ (lo & 7)) * 8)];
                    sa1 = __builtin_amdgcn_mfma_f32_32x32x16_bf16(kf3, qf[3], sa1, 0, 0, 0);
                }
                __builtin_amdgcn_s_setprio(0);
                const bool mb = (it == q2);
                float pv[16];
                #pragma unroll
                for (int r = 0; r < 16; ++r) {
                    float e = __expf(sa0[r] + sa1[r]);
                    if (mb) {
                        const int srow = it * 64 + eu * 32 + (r & 3) + 8 * (r >> 2) + 4 * hi;
                        if (srow > qrow) e = 0.f;
                    }
                    pv[r] = e;
                    lp += e;
                }
                unsigned int d0 = pk2(pv[0], pv[1]),   d1 = pk2(pv[2], pv[3]);
                unsigned int d2 = pk2(pv[4], pv[5]),   d3 = pk2(pv[6], pv[7]);
                unsigned int d4 = pk2(pv[8], pv[9]),   d5 = pk2(pv[10], pv[11]);
                unsigned int d6 = pk2(pv[12], pv[13]), d7 = pk2(pv[14], pv[15]);
                u32x4 fa0, fa1;
#if __has_builtin(__builtin_amdgcn_permlane32_swap)
                {
                    u32x2 s02 = __builtin_bit_cast(u32x2, __builtin_amdgcn_permlane32_swap(d0, d2, false, false));
                    u32x2 s13 = __builtin_bit_cast(u32x2, __builtin_amdgcn_permlane32_swap(d1, d3, false, false));
                    u32x2 s46 = __builtin_bit_cast(u32x2, __builtin_amdgcn_permlane32_swap(d4, d6, false, false));
                    u32x2 s57 = __builtin_bit_cast(u32x2, __builtin_amdgcn_permlane32_swap(d5, d7, false, false));
                    fa0 = (u32x4){s02[0], s13[0], s02[1], s13[1]};
                    fa1 = (u32x4){s46[0], s57[0], s46[1], s57[1]};
                }
#else
                {
                    unsigned int sA0 = hi ? d0 : d2, sA1 = hi ? d1 : d3;
                    unsigned int rA0 = (unsigned int)__shfl_xor((int)sA0, 32);
                    unsigned int rA1 = (unsigned int)__shfl_xor((int)sA1, 32);
                    fa0 = hi ? (u32x4){rA0, rA1, d2, d3} : (u32x4){d0, d1, rA0, rA1};
                    unsigned int sB0 = hi ? d4 : d6, sB1 = hi ? d5 : d7;
                    unsigned int rB0 = (unsigned int)__shfl_xor((int)sB0, 32);
                    unsigned int rB1 = (unsigned int)__shfl_xor((int)sB1, 32);
                    fa1 = hi ? (u32x4){rB0, rB1, d6, d7} : (u32x4){d4, d5, rB0, rB1};
                }
#endif
                *(s16x8*)&lds[45056 + kb * 4096 + (qh * 2 + eu) * 1024 + l * 8]       = __builtin_bit_cast(s16x8, fa0);
                *(s16x8*)&lds[45056 + kb * 4096 + (qh * 2 + eu) * 1024 + 512 + l * 8] = __builtin_bit_cast(s16x8, fa1);
            }

            // ---- consume P of tile it-1 (written last iter; visible since barrier) ----
            if (it > 0) {
                const int vp = (vi == 0) ? 2 : vi - 1;
                PVSTEP(vp, 1 - kb);
            }

            vi = vn; vn = (vn == 2) ? 0 : vn + 1;
        }
        __syncthreads();           // last pl writes visible to all waves; kl dead -> stL may overlay
        {
            const int vlast = (vi == 0) ? 2 : vi - 1;   // vl slot of tile q2
            PVSTEP(vlast, q2 & 1);
        }
        if (isprod) {              // row totals -> stL (overlays dead kl region)
            float lt = lp + __shfl_xor(lp, 32);
            if (hi == 0) ((float*)lds)[(qh * 2 + eu) * 32 + lo] = lt;
        }
        __syncthreads();

        // epilogue: every wave writes its (qh, eu) 32x32 O block, normalized (oa+ob merged here)
        {
            const float* stL = (const float*)lds;   // [2 qh][2 ss][32]
            #pragma unroll
            for (int r = 0; r < 16; ++r) {
                const int rloc = (r & 3) + 8 * (r >> 2) + 4 * hi;
                const float linv = 1.f / (stL[(qh * 2) * 32 + rloc] + stL[(qh * 2 + 1) * 32 + rloc]);
                out[((size_t)bb * TT + q0 + qh * 32 + rloc) * DD + e0 + eu * 32 + lo]
                    = (oa[r] + ob[r]) * linv;
            }
        }
        __syncthreads();           // all stL reads + vl/pl reads done before next half re-stages
    }
    #undef STAGE
    #undef PVSTEP
}

extern "C" void kernel_launch(void* const* d_in, const int* in_sizes, int n_in,
                              void* d_out, int out_size, void* d_ws, size_t ws_size,
                              hipStream_t stream)
{
    const float* x  = (const float*)d_in[0];
    const float* Wq = (const float*)d_in[1];
    const float* Wk = (const float*)d_in[2];
    const float* Wv = (const float*)d_in[3];

    // ws: q [0,2M) | k [2M,4M) | vT [4M,16M) | xbf [16M,28M) | wall [28M,28.4M)
    unsigned short* qws  = (unsigned short*)d_ws;
    unsigned short* kws  = (unsigned short*)((char*)d_ws + ((size_t)2 << 20));
    unsigned short* vtws = (unsigned short*)((char*)d_ws + ((size_t)4 << 20));
    unsigned short* xbf  = (unsigned short*)((char*)d_ws + ((size_t)16 << 20));
    unsigned short* wall = (unsigned short*)((char*)d_ws + ((size_t)28 << 20));

    xprep<<<dim3(3072), dim3(256), 0, stream>>>(x, xbf);
    wprep<<<dim3(24), dim3(256), 0, stream>>>(Wq, Wk, Wv, wall);
    qkv_gemm<<<dim3(256, 4), dim3(256), 0, stream>>>(xbf, wall, qws, kws, vtws);
    attn<<<dim3(256), dim3(768), 0, stream>>>(qws, kws, vtws, (float*)d_out);
}

// Round 10
// 126.003 us; speedup vs baseline: 1.0741x; 1.0741x over previous
//
#include <hip/hip_runtime.h>

#define TT 2048
#define DD 384

typedef float f32x4 __attribute__((ext_vector_type(4)));
typedef float f32x16 __attribute__((ext_vector_type(16)));
typedef short s16x8 __attribute__((ext_vector_type(8)));
typedef short s16x2 __attribute__((ext_vector_type(2)));
typedef unsigned int u32x4 __attribute__((ext_vector_type(4)));
typedef unsigned int u32x2 __attribute__((ext_vector_type(2)));

typedef __attribute__((address_space(3))) unsigned char* as3p;
typedef const __attribute__((address_space(1))) unsigned char* as1p;
// HW direct global->LDS copy: 16B/lane x 64 lanes = 1KB per call; LDS dest = uniform base + lane*16.
#define GLLDS(gsrc, ldst) __builtin_amdgcn_global_load_lds((as1p)(gsrc), (as3p)(ldst), 16, 0, 0)

static __device__ __forceinline__ unsigned short f2bf(float f) {
    unsigned int u = __builtin_bit_cast(unsigned int, f);
    u = (u + 0x7fffu + ((u >> 16) & 1u)) >> 16;
    return (unsigned short)u;
}
static __device__ __forceinline__ unsigned int pk2(float a, float b) {
#if __has_builtin(__builtin_amdgcn_cvt_pk_bf16_f32)
    s16x2 t = __builtin_amdgcn_cvt_pk_bf16_f32(a, b);
    return __builtin_bit_cast(unsigned int, t);
#else
    unsigned int ua = __builtin_bit_cast(unsigned int, a);
    unsigned int ub = __builtin_bit_cast(unsigned int, b);
    ua = (ua + 0x7fffu + ((ua >> 16) & 1u)) >> 16;
    ub = (ub + 0x7fffu + ((ub >> 16) & 1u)) & 0xffff0000u;
    return ua | ub;
#endif
}

// ---------------- W pre-conversion: wall[512 col][384 k] bf16, B-tile LDS-image swizzle ----------
// col 0..63 = Wq, 64..127 = Wk, 128..511 = Wv. Within each (col, 32-k group): chunk c stored at
// c ^ (col&3) — the exact image qkv_gemm's B-frag reads expect, so staging is pure global_load_lds.
__global__ __launch_bounds__(256, 8) void wprep(
    const float* __restrict__ Wq, const float* __restrict__ Wk, const float* __restrict__ Wv,
    unsigned short* __restrict__ wall)
{
    const int gid = blockIdx.x * 256 + threadIdx.x;   // 6144 = 512 cols x 12 k-groups
    const int col = gid & 511;
    const int kt  = gid >> 9;
    unsigned short* op = wall + (size_t)col * 384 + kt * 32;
    #pragma unroll
    for (int c = 0; c < 4; ++c) {
        u32x4 v;
        #pragma unroll
        for (int j2 = 0; j2 < 4; ++j2) {
            const int k = kt * 32 + c * 8 + j2 * 2;
            float f0 = (col < 64)  ? Wq[(size_t)k * 64 + col]
                     : (col < 128) ? Wk[(size_t)k * 64 + (col - 64)]
                                   : Wv[(size_t)k * 384 + (col - 128)];
            float f1 = (col < 64)  ? Wq[(size_t)(k + 1) * 64 + col]
                     : (col < 128) ? Wk[(size_t)(k + 1) * 64 + (col - 64)]
                                   : Wv[(size_t)(k + 1) * 384 + (col - 128)];
            v[j2] = pk2(f0, f1);
        }
        *(s16x8*)(op + ((c ^ (col & 3)) * 8)) = __builtin_bit_cast(s16x8, v);
    }
}

// ---------------- fused QKV projection GEMM (R8, proven): 64x128 tiles, GLLDS-B, 4 blocks/CU -----
// Grid (256,4): 1024 blocks -> 4/CU, 4 waves/SIMD. A (x tile) inline fp32->bf16 (1 f32x4-pair load
// + 4 pk2 + 1 b128 write per thread per kt); B staged via 2 global_load_lds per wave from
// pre-swizzled wall. Single-barrier dbuf skeleton. Outputs: q natural (1/8), k pre-swizzled,
// vT transposed pre-swizzled (verbatim attn images).
__global__ __launch_bounds__(256, 4) void qkv_gemm(
    const float* __restrict__ x, const unsigned short* __restrict__ wall,
    unsigned short* __restrict__ qo, unsigned short* __restrict__ ko,
    unsigned short* __restrict__ vto)
{
    __shared__ __align__(16) unsigned short lds[12288];   // 2 bufs x (A 2048 | B 4096) ush
    const int tid = threadIdx.x;
    const int l   = tid & 63;
    const int w   = tid >> 6;
    const int si  = l & 15;
    const int qq  = l >> 4;
    const int m0  = blockIdx.x * 64;
    const int nb  = blockIdx.y;
    const int wr  = w >> 1, wc = w & 1;

    const int ar = tid >> 2, ac = tid & 3;                 // A staging: row 0..63, chunk 0..3
    const float* xs = x + (size_t)(m0 + ar) * DD + ac * 8;
    const unsigned short* ws = wall + (size_t)nb * 128 * 384;   // this nb's 128-col panel

#define QSTAGE(KT, B)                                                                      \
    {                                                                                      \
        _Pragma("unroll")                                                                  \
        for (int c2 = 0; c2 < 2; ++c2) {                                                   \
            const int ch = w * 2 + c2;                                                     \
            GLLDS(ws + (size_t)(ch * 16 + (l >> 2)) * 384 + (KT) * 32 + (l & 3) * 8,       \
                  &lds[(B) * 6144 + 2048 + ch * 512]);                                     \
        }                                                                                  \
        f32x4 x0 = *(const f32x4*)(xs + (KT) * 32);                                        \
        f32x4 x1 = *(const f32x4*)(xs + (KT) * 32 + 4);                                    \
        u32x4 av = (u32x4){pk2(x0[0], x0[1]), pk2(x0[2], x0[3]),                           \
                           pk2(x1[0], x1[1]), pk2(x1[2], x1[3])};                          \
        *(s16x8*)&lds[(B) * 6144 + ar * 32 + ((ac ^ (ar & 3)) * 8)] =                      \
            __builtin_bit_cast(s16x8, av);                                                 \
    }

    f32x4 acc[2][4];
    #pragma unroll
    for (int rt = 0; rt < 2; ++rt)
        #pragma unroll
        for (int ct = 0; ct < 4; ++ct) acc[rt][ct] = (f32x4){0.f, 0.f, 0.f, 0.f};

    QSTAGE(0, 0);
    for (int kt = 0; kt < 12; ++kt) {
        const int b = kt & 1;
        __syncthreads();                       // vmcnt(0)+lgkmcnt(0)+barrier: buf b staged
        if (kt < 11) QSTAGE(kt + 1, 1 - b);

        s16x8 af[2], bf[4];
        #pragma unroll
        for (int rt = 0; rt < 2; ++rt) {
            const int row = wr * 32 + rt * 16 + si;
            af[rt] = *(const s16x8*)&lds[b * 6144 + row * 32 + ((qq ^ (row & 3)) * 8)];
        }
        #pragma unroll
        for (int ct = 0; ct < 4; ++ct) {
            const int col = wc * 64 + ct * 16 + si;
            bf[ct] = *(const s16x8*)&lds[b * 6144 + 2048 + col * 32 + ((qq ^ (col & 3)) * 8)];
        }
        #pragma unroll
        for (int rt = 0; rt < 2; ++rt)
            #pragma unroll
            for (int ct = 0; ct < 4; ++ct)
                acc[rt][ct] = __builtin_amdgcn_mfma_f32_16x16x32_bf16(af[rt], bf[ct], acc[rt][ct], 0, 0, 0);
    }
    __syncthreads();                           // all frag reads done before epilogue overlays LDS
#undef QSTAGE

    if (nb == 0) {
        if (wc == 0) {  // q: natural layout, fold 1/sqrt(K)
            #pragma unroll
            for (int rt = 0; rt < 2; ++rt)
                #pragma unroll
                for (int ct = 0; ct < 4; ++ct)
                    #pragma unroll
                    for (int r = 0; r < 4; ++r) {
                        const int m = m0 + wr * 32 + rt * 16 + qq * 4 + r;
                        qo[(size_t)m * 64 + ct * 16 + si] = f2bf(acc[rt][ct][r] * 0.125f);
                    }
        } else {        // k: pre-swizzled (chunk c -> c ^ (t&7))
            #pragma unroll
            for (int rt = 0; rt < 2; ++rt)
                #pragma unroll
                for (int ct = 0; ct < 4; ++ct)
                    #pragma unroll
                    for (int r = 0; r < 4; ++r) {
                        const int m = m0 + wr * 32 + rt * 16 + qq * 4 + r;
                        const int col = ct * 16 + si;
                        ko[(size_t)m * 64 + (((col >> 3) ^ (m & 7)) * 8) + (col & 7)] = f2bf(acc[rt][ct][r]);
                    }
        }
    } else {            // vT: transpose in LDS (pre-swizzled image), then linear 16B copy-out
        #pragma unroll
        for (int rt = 0; rt < 2; ++rt)
            #pragma unroll
            for (int ct = 0; ct < 4; ++ct)
                #pragma unroll
                for (int r = 0; r < 4; ++r) {
                    const int m = wr * 32 + rt * 16 + qq * 4 + r;   // local 0..63
                    const int n = wc * 64 + ct * 16 + si;           // 0..127
                    lds[n * 64 + (((m >> 3) ^ (n & 7)) * 8) + (m & 7)] = f2bf(acc[rt][ct][r]);
                }
        __syncthreads();
        const int bbat = m0 >> 11, t0 = m0 & 2047;
        #pragma unroll
        for (int i = 0; i < 4; ++i) {
            const int u = tid + 256 * i, n = u >> 3, p = u & 7;
            *(s16x8*)&vto[((size_t)bbat * DD + ((nb - 1) * 128 + n)) * TT + t0 + p * 8]
                = *(const s16x8*)&lds[n * 64 + p * 8];
        }
    }
}

// ---------------- fused causal attention R10: 16-wave full role-specialization ----------------
// R6 structure (constant-work paired blocks, 256 blocks, lag-1 P pipeline, single barrier/iter,
// V tbuf + K/P dbuf) with waves SPLIT BY ROLE at constant per-wave work: waves 0-3 = pure
// producers (one (qh,ss) P-subtile each: QK 4-MFMA + exp + permlane pack; stage 2 K-chunks) —
// exactly R6's producer load MINUS its PVSTEP; waves 4-15 = pure consumers (one (qh,eu) 32x32
// output block each, PVSTEP verbatim; stage 2 V-chunks). Barrier period drops from the producer's
// [produce+consume] chain to max(produce, consume). Per-(qh,eu) PV sequence and P data identical
// -> outputs bit-identical to R6/R8 (absmax canary 0.03125).
__global__ __launch_bounds__(1024, 4) void attn(
    const unsigned short* __restrict__ qg, const unsigned short* __restrict__ kg,
    const unsigned short* __restrict__ vg, float* __restrict__ out)
{
    // ush map: kl [0,8192) = 2 x [64 t][64] | vl [8192,45056) = 3 x [192 e][64 t]
    //          pl [45056,53248) = 2 x [2 qh][2 ss][a0:512|a1:512] | stL overlays kl after loop
    __shared__ __align__(16) unsigned short lds[53248];

    const int tid = threadIdx.x;
    const int l   = tid & 63;
    const int w   = tid >> 6;     // 0..15
    const bool isprod = (w < 4);  // waves 0-3 produce; 4-15 consume
    const int qh  = isprod ? (w & 1) : ((w - 4) & 1);       // 32-row q half
    const int su  = isprod ? (w >> 1) : ((w - 4) >> 1);     // producer: ss 0/1; consumer: eu 0..5
    const int lo  = l & 31;
    const int hi  = l >> 5;

    const int g  = blockIdx.x;    // 0..255
    const int bb = g & 7;
    const int eh = (g >> 3) & 1;
    const int pr = g >> 4;        // 0..15 pair id
    const int e0 = eh * 192;

    const unsigned short* kbase = kg + (size_t)bb * TT * 64;
    const unsigned short* vbase = vg + ((size_t)bb * DD + e0) * TT;

    // staging: K 8 chunks by producers (2 each); V 24 chunks by the 12 consumers (2 each)
    #define STAGE(IT, KB, VB)                                                              \
    {                                                                                      \
        if (isprod) {                                                                      \
            GLLDS(kbase + (size_t)(IT) * 4096 + (2 * w) * 512 + l * 8,                     \
                  &lds[(KB) * 4096 + (2 * w) * 512]);                                      \
            GLLDS(kbase + (size_t)(IT) * 4096 + (2 * w + 1) * 512 + l * 8,                 \
                  &lds[(KB) * 4096 + (2 * w + 1) * 512]);                                  \
        } else {                                                                           \
            _Pragma("unroll")                                                              \
            for (int c2 = 0; c2 < 2; ++c2) {                                               \
                const int rg = 2 * (w - 4) + c2;                                           \
                GLLDS(vbase + (size_t)(rg * 8 + (l >> 3)) * TT + (IT) * 64 + (l & 7) * 8,  \
                      &lds[8192 + (VB) * 12288 + rg * 512]);                               \
            }                                                                              \
        }                                                                                  \
    }

    // consumer PV of one s-tile from vl[VB], pl[PB]: this wave's (qh, eu=su) 32q x 32e block
    #define PVSTEP(VB, PB)                                                                 \
    {                                                                                      \
        __builtin_amdgcn_s_setprio(1);                                                     \
        _Pragma("unroll")                                                                  \
        for (int ss = 0; ss < 2; ++ss) {                                                   \
            const int pbse = 45056 + (PB) * 4096 + (qh * 2 + ss) * 1024;                   \
            s16x8 a0 = *(const s16x8*)&lds[pbse + l * 8];                                  \
            s16x8 a1 = *(const s16x8*)&lds[pbse + 512 + l * 8];                            \
            const int el = su * 32 + lo;                                                   \
            const int vbse = 8192 + (VB) * 12288 + el * 64;                                \
            s16x8 v0 = *(const s16x8*)&lds[vbse + (((ss * 4 + hi) ^ (el & 7)) * 8)];       \
            o = __builtin_amdgcn_mfma_f32_32x32x16_bf16(a0, v0, o, 0, 0, 0);               \
            s16x8 v1 = *(const s16x8*)&lds[vbse + (((ss * 4 + 2 + hi) ^ (el & 7)) * 8)];   \
            o = __builtin_amdgcn_mfma_f32_32x32x16_bf16(a1, v1, o, 0, 0, 0);               \
        }                                                                                  \
        __builtin_amdgcn_s_setprio(0);                                                     \
    }

    for (int hf = 0; hf < 2; ++hf) {
        const int q2 = hf ? pr : 31 - pr;      // heavy tile first, then its complement
        const int q0 = q2 * 64;
        const int qrow = q0 + qh * 32 + lo;

        // Q as B-operand frags (pre-scaled 1/8, natural layout) — producers only
        s16x8 qf[4];
        if (isprod) {
            const unsigned short* qp = qg + ((size_t)bb * TT + qrow) * 64;
            #pragma unroll
            for (int st = 0; st < 4; ++st) qf[st] = *(const s16x8*)(qp + st * 16 + hi * 8);
        }

        f32x16 o;
        #pragma unroll
        for (int r = 0; r < 16; ++r) o[r] = 0.f;
        float lp = 0.f;

        STAGE(0, 0, 0);   // prologue: tile 0 -> kl0 / vl0

        int vi = 0, vn = 1;   // vl slot of tile it, it+1 (mod 3); tile it-1 sits at the third slot
        for (int it = 0; it <= q2; ++it) {
            const int kb = it & 1;
            __syncthreads();   // vmcnt(0)+barrier: staging for tile it complete; pl[kb] free

            if (it < q2) STAGE(it + 1, 1 - kb, vn);   // in flight during compute

            if (isprod) {   // ---- produce P-subtile (qh, ss=su) of tile it -> pl[kb] ----
                f32x16 sa;
                #pragma unroll
                for (int r = 0; r < 16; ++r) sa[r] = 0.f;
                __builtin_amdgcn_s_setprio(1);
                #pragma unroll
                for (int st = 0; st < 4; ++st) {
                    s16x8 kf = *(const s16x8*)&lds[kb * 4096 + (su * 32 + lo) * 64 + (((st * 2 + hi) ^ (lo & 7)) * 8)];
                    sa = __builtin_amdgcn_mfma_f32_32x32x16_bf16(kf, qf[st], sa, 0, 0, 0);
                }
                __builtin_amdgcn_s_setprio(0);
                const bool mb = (it == q2);
                float pv[16];
                #pragma unroll
                for (int r = 0; r < 16; ++r) {
                    float e = __expf(sa[r]);
                    if (mb) {
                        const int srow = it * 64 + su * 32 + (r & 3) + 8 * (r >> 2) + 4 * hi;
                        if (srow > qrow) e = 0.f;
                    }
                    pv[r] = e;
                    lp += e;
                }
                unsigned int d0 = pk2(pv[0], pv[1]),   d1 = pk2(pv[2], pv[3]);
                unsigned int d2 = pk2(pv[4], pv[5]),   d3 = pk2(pv[6], pv[7]);
                unsigned int d4 = pk2(pv[8], pv[9]),   d5 = pk2(pv[10], pv[11]);
                unsigned int d6 = pk2(pv[12], pv[13]), d7 = pk2(pv[14], pv[15]);
                u32x4 fa0, fa1;
#if __has_builtin(__builtin_amdgcn_permlane32_swap)
                {
                    u32x2 s02 = __builtin_bit_cast(u32x2, __builtin_amdgcn_permlane32_swap(d0, d2, false, false));
                    u32x2 s13 = __builtin_bit_cast(u32x2, __builtin_amdgcn_permlane32_swap(d1, d3, false, false));
                    u32x2 s46 = __builtin_bit_cast(u32x2, __builtin_amdgcn_permlane32_swap(d4, d6, false, false));
                    u32x2 s57 = __builtin_bit_cast(u32x2, __builtin_amdgcn_permlane32_swap(d5, d7, false, false));
                    fa0 = (u32x4){s02[0], s13[0], s02[1], s13[1]};
                    fa1 = (u32x4){s46[0], s57[0], s46[1], s57[1]};
                }
#else
                {
                    unsigned int sA0 = hi ? d0 : d2, sA1 = hi ? d1 : d3;
                    unsigned int rA0 = (unsigned int)__shfl_xor((int)sA0, 32);
                    unsigned int rA1 = (unsigned int)__shfl_xor((int)sA1, 32);
                    fa0 = hi ? (u32x4){rA0, rA1, d2, d3} : (u32x4){d0, d1, rA0, rA1};
                    unsigned int sB0 = hi ? d4 : d6, sB1 = hi ? d5 : d7;
                    unsigned int rB0 = (unsigned int)__shfl_xor((int)sB0, 32);
                    unsigned int rB1 = (unsigned int)__shfl_xor((int)sB1, 32);
                    fa1 = hi ? (u32x4){rB0, rB1, d6, d7} : (u32x4){d4, d5, rB0, rB1};
                }
#endif
                *(s16x8*)&lds[45056 + kb * 4096 + (qh * 2 + su) * 1024 + l * 8]       = __builtin_bit_cast(s16x8, fa0);
                *(s16x8*)&lds[45056 + kb * 4096 + (qh * 2 + su) * 1024 + 512 + l * 8] = __builtin_bit_cast(s16x8, fa1);
            } else if (it > 0) {
                // ---- consume P of tile it-1 (written last iter; visible since barrier) ----
                const int vp = (vi == 0) ? 2 : vi - 1;
                PVSTEP(vp, 1 - kb);
            }

            vi = vn; vn = (vn == 2) ? 0 : vn + 1;
        }
        __syncthreads();           // last pl writes visible to all waves; kl dead -> stL may overlay

        if (isprod) {              // row totals -> stL (overlays dead kl region)
            float lt = lp + __shfl_xor(lp, 32);
            if (hi == 0) ((float*)lds)[(qh * 2 + su) * 32 + lo] = lt;
        } else {                   // tail: PV for tile q2 (concurrent with stL writes; no overlap)
            const int vlast = (vi == 0) ? 2 : vi - 1;
            PVSTEP(vlast, q2 & 1);
        }
        __syncthreads();

        if (!isprod) {             // epilogue: consumer writes its (qh, eu) 32x32 block, normalized
            const float* stL = (const float*)lds;   // [2 qh][2 ss][32]
            #pragma unroll
            for (int r = 0; r < 16; ++r) {
                const int rloc = (r & 3) + 8 * (r >> 2) + 4 * hi;
                const float linv = 1.f / (stL[(qh * 2) * 32 + rloc] + stL[(qh * 2 + 1) * 32 + rloc]);
                out[((size_t)bb * TT + q0 + qh * 32 + rloc) * DD + e0 + su * 32 + lo]
                    = o[r] * linv;
            }
        }
        __syncthreads();           // all stL reads + vl/pl reads done before next half re-stages
    }
    #undef STAGE
    #undef PVSTEP
}

extern "C" void kernel_launch(void* const* d_in, const int* in_sizes, int n_in,
                              void* d_out, int out_size, void* d_ws, size_t ws_size,
                              hipStream_t stream)
{
    const float* x  = (const float*)d_in[0];
    const float* Wq = (const float*)d_in[1];
    const float* Wk = (const float*)d_in[2];
    const float* Wv = (const float*)d_in[3];

    // ws: q [0,2M) | k [2M,4M) | vT [4M,16M) | wall [16M,16M+0.4M)
    unsigned short* qws  = (unsigned short*)d_ws;
    unsigned short* kws  = (unsigned short*)((char*)d_ws + ((size_t)2 << 20));
    unsigned short* vtws = (unsigned short*)((char*)d_ws + ((size_t)4 << 20));
    unsigned short* wall = (unsigned short*)((char*)d_ws + ((size_t)16 << 20));

    wprep<<<dim3(24), dim3(256), 0, stream>>>(Wq, Wk, Wv, wall);
    qkv_gemm<<<dim3(256, 4), dim3(256), 0, stream>>>(x, wall, qws, kws, vtws);
    attn<<<dim3(256), dim3(1024), 0, stream>>>(qws, kws, vtws, (float*)d_out);
}